// Round 8
// baseline (389.665 us; speedup 1.0000x reference)
//
#include <hip/hip_runtime.h>

#define NN 8192
#define DIM 64
#define NR 5
#define BM 512      // output rows per block
#define BK 512      // K window per block = 2 phases x 256
#define PHK 256     // K per staged phase (8 ktiles of 32)

typedef __attribute__((ext_vector_type(8))) short short8;
typedef __attribute__((ext_vector_type(4))) float f32x4;

__device__ inline unsigned short f2bf(float x) {
    unsigned u = __float_as_uint(x);
    return (unsigned short)((u + 0x7FFFu + ((u >> 16) & 1u)) >> 16);
}

__device__ inline int swz5(int row) { return (row ^ (row >> 5)) & 31; }

// P fragment linear index (shorts) for (r, k, o).
// Bijection within a ktile: g=(k>>3)&3, j=k&7. The A-mask build uses the same
// (g,j)->k map, so the permutation cancels inside the MFMA.
__device__ inline size_t pfrag_idx(int r, int k, int o) {
    int ktile = k >> 5;
    int g     = (k >> 3) & 3;
    int j     = k & 7;
    int lane  = g * 16 + (o & 15);
    int n     = o >> 4;
    return ((((size_t)r * (NN / 32) + ktile) * 4 + n) * 64 + lane) * 8 + j;
}

// ---------------- zero-init ----------------
__global__ __launch_bounds__(256) void zero_k(float* __restrict__ outp,
                                              unsigned* __restrict__ deg)
{
    const int stride = gridDim.x * blockDim.x;
    int i = blockIdx.x * blockDim.x + threadIdx.x;
    int4 z = {0, 0, 0, 0};
    for (int idx = i; idx < 2 * NN * DIM / 4; idx += stride) ((int4*)outp)[idx] = z;
    for (int idx = i; idx < 2 * NN / 4; idx += stride) ((int4*)deg)[idx] = z;
}

// ---------------- P precompute: P[r][v][o] = sum_f feat[v][f] * W[r][f][o] ----
__global__ __launch_bounds__(256) void precompute_P(
    const float* __restrict__ u_feat, const float* __restrict__ v_feat,
    const float* __restrict__ w_u, const float* __restrict__ w_v,
    unsigned short* __restrict__ p_u, unsigned short* __restrict__ p_v)
{
    int wid  = (blockIdx.x * blockDim.x + threadIdx.x) >> 6;
    int lane = threadIdx.x & 63;
    const int tasks = 2 * NR * (NN / 32);
    if (wid >= tasks) return;
    int dir  = wid / (NR * (NN / 32));
    int rem  = wid % (NR * (NN / 32));
    int r    = rem / (NN / 32);
    int v0   = (rem % (NN / 32)) * 32;

    const float* feat = dir ? u_feat : v_feat;
    const float* w    = dir ? w_v : w_u;
    unsigned short* dst = dir ? p_v : p_u;

    float wreg[DIM];
#pragma unroll
    for (int f = 0; f < DIM; ++f) wreg[f] = w[(r * DIM + f) * DIM + lane];

    for (int v = v0; v < v0 + 32; ++v) {
        float x = feat[(size_t)v * DIM + lane];
        float acc = 0.f;
#pragma unroll
        for (int f = 0; f < DIM; ++f) acc += __shfl(x, f) * wreg[f];
        dst[pfrag_idx(r, v, lane)] = f2bf(acc);
    }
}

// ---------------- masked GEMM, both directions in one launch ----------------
// blockIdx.z = dir (0: rows=u,k=v ; 1: rows=v,k=u).
// 512 thr = 8 waves; wave owns 64 rows (4 m-tiles) x all 4 n -> 20KB B per
// step feeds 80 MFMAs (2x better B-bytes/MFMA than R7). Raw s_barrier per
// step phase-locks waves so the 20KB B slice stays L1-resident.
// Nibble tile [512][128B], swizzle: dword d stored at d ^ swz5(row).
__global__ __launch_bounds__(512, 4) void gemm_both(
    const int* __restrict__ adj,
    const unsigned short* __restrict__ p_u, const unsigned short* __restrict__ p_v,
    float* __restrict__ outp, unsigned int* __restrict__ deg)
{
    __shared__ unsigned char tile[BM][PHK / 2];   // 64 KB (nibbles)
    __shared__ unsigned int  cnt[BM];             // dir0 row counts

    const int tid  = threadIdx.x;
    const int lane = tid & 63;
    const int wv   = tid >> 6;
    const int dir  = blockIdx.z;
    const int b0   = blockIdx.x * BM;     // output-row base
    const int k0   = blockIdx.y * BK;     // K base
    const int g    = lane >> 4;
    const int c15  = lane & 15;

    const unsigned short* pfrag = dir ? p_v : p_u;
    float* out = outp + (size_t)dir * NN * DIM;
    unsigned* dg = deg + dir * NN;

    cnt[tid] = 0;
    unsigned scnt0 = 0, scnt1 = 0;   // dir1: 4 x 16-bit column counters
    __syncthreads();

    f32x4 acc[4][4];
#pragma unroll
    for (int m = 0; m < 4; ++m)
#pragma unroll
        for (int n = 0; n < 4; ++n) acc[m][n] = (f32x4){0.f, 0.f, 0.f, 0.f};

    unsigned* t32 = (unsigned*)&tile[0][0];

    for (int ph = 0; ph < 2; ++ph) {
        const int kp = k0 + ph * PHK;
        if (ph) __syncthreads();          // phase-0 compute done; safe to overwrite

        // ================= staging =================
        if (dir == 0) {
            const int sub = tid & 15;          // 16 threads per row
            const int rq  = tid >> 4;          // 32 rows per round
#pragma unroll 2
            for (int rnd = 0; rnd < 16; ++rnd) {
                int row = rnd * 32 + rq;
                const int* bp = adj + (size_t)(b0 + row) * NN + kp + sub * 4;
                int4 A0 = *(const int4*)(bp);
                int4 A1 = *(const int4*)(bp + 64);
                int4 A2 = *(const int4*)(bp + 128);
                int4 A3 = *(const int4*)(bp + 192);
                int c = 0;
                int4 As[4] = {A0, A1, A2, A3};
#pragma unroll
                for (int it = 0; it < 4; ++it) {
                    int4 a = As[it];
                    c += (a.x != 0) + (a.y != 0) + (a.z != 0) + (a.w != 0);
                    unsigned pk = (unsigned)a.x | ((unsigned)a.y << 4) |
                                  ((unsigned)a.z << 8) | ((unsigned)a.w << 12);
                    int dd = it * 8 + (sub >> 1);
                    int dp = dd ^ swz5(row);
                    *(unsigned short*)&tile[row][dp * 4 + (sub & 1) * 2] = (unsigned short)pk;
                }
                c += __shfl_xor(c, 1); c += __shfl_xor(c, 2);
                c += __shfl_xor(c, 4); c += __shfl_xor(c, 8);
                if (sub == 0) cnt[row] += (unsigned)c;
            }
        } else {
            const int v4 = (tid & 127) * 4;
            const int uq = tid >> 7;
#pragma unroll 2
            for (int rnd = 0; rnd < 16; ++rnd) {
                int u4 = rnd * 16 + uq * 4;
                int4 P0 = *(const int4*)(adj + (size_t)(kp + u4 + 0) * NN + b0 + v4);
                int4 P1 = *(const int4*)(adj + (size_t)(kp + u4 + 1) * NN + b0 + v4);
                int4 P2 = *(const int4*)(adj + (size_t)(kp + u4 + 2) * NN + b0 + v4);
                int4 P3 = *(const int4*)(adj + (size_t)(kp + u4 + 3) * NN + b0 + v4);
                const int* q0 = (const int*)&P0; const int* q1 = (const int*)&P1;
                const int* q2 = (const int*)&P2; const int* q3 = (const int*)&P3;
                int dd = rnd * 2 + (uq >> 1);
#pragma unroll
                for (int cc = 0; cc < 4; ++cc) {
                    int x0 = q0[cc], x1 = q1[cc], x2 = q2[cc], x3 = q3[cc];
                    unsigned pk = (unsigned)x0 | ((unsigned)x1 << 4) |
                                  ((unsigned)x2 << 8) | ((unsigned)x3 << 12);
                    int row = v4 + cc;
                    int dp  = dd ^ swz5(row);
                    *(unsigned short*)&tile[row][dp * 4 + (uq & 1) * 2] = (unsigned short)pk;
                    unsigned ca = (unsigned)((x0 != 0) + (x1 != 0) + (x2 != 0) + (x3 != 0));
                    if (cc == 0) scnt0 += ca;
                    else if (cc == 1) scnt0 += ca << 16;
                    else if (cc == 2) scnt1 += ca;
                    else scnt1 += ca << 16;
                }
            }
        }
        __syncthreads();

        // ================= 8 MFMA steps, raw-barrier lockstep =================
        const unsigned short* pb[NR];
#pragma unroll
        for (int r = 0; r < NR; ++r)
            pb[r] = pfrag + ((size_t)(r * (NN / 32) + (k0 >> 5) + ph * 8) * 4) * 512 + lane * 8;

        for (int s = 0; s < 8; ++s) {
            unsigned nib[4];
#pragma unroll
            for (int m = 0; m < 4; ++m) {
                int row = wv * 64 + m * 16 + c15;
                int dp  = (s * 4 + g) ^ swz5(row);
                nib[m] = t32[row * 32 + dp];
            }
#pragma unroll
            for (int r = 0; r < NR; ++r) {
                short8 am[4];
#pragma unroll
                for (int m = 0; m < 4; ++m)
#pragma unroll
                    for (int j = 0; j < 8; ++j)
                        am[m][j] = (short)((((nib[m] >> (4 * j)) & 0xFu) == (unsigned)(r + 1)) ? 0x3F80 : 0);
#pragma unroll
                for (int n = 0; n < 4; ++n) {
                    short8 bf = *(const short8*)(pb[r] + n * 512);
                    acc[0][n] = __builtin_amdgcn_mfma_f32_16x16x32_bf16(am[0], bf, acc[0][n], 0, 0, 0);
                    acc[1][n] = __builtin_amdgcn_mfma_f32_16x16x32_bf16(am[1], bf, acc[1][n], 0, 0, 0);
                    acc[2][n] = __builtin_amdgcn_mfma_f32_16x16x32_bf16(am[2], bf, acc[2][n], 0, 0, 0);
                    acc[3][n] = __builtin_amdgcn_mfma_f32_16x16x32_bf16(am[3], bf, acc[3][n], 0, 0, 0);
                }
            }
#pragma unroll
            for (int r = 0; r < NR; ++r) pb[r] += 2048;   // +1 ktile
            __builtin_amdgcn_s_barrier();                 // rendezvous only
        }
    }

    // ================= epilogue: C atomics (col=c15, row=g*4+q) =================
#pragma unroll
    for (int m = 0; m < 4; ++m) {
        int rbase = b0 + wv * 64 + m * 16 + g * 4;
#pragma unroll
        for (int n = 0; n < 4; ++n)
#pragma unroll
            for (int q = 0; q < 4; ++q)
                atomicAdd(&out[(size_t)(rbase + q) * DIM + n * 16 + c15], acc[m][n][q]);
    }

    // ================= degree reductions =================
    if (dir == 0) {
        atomicAdd(&dg[b0 + tid], cnt[tid]);
    } else {
        __syncthreads();                 // all tile reads done; reuse as scratch
        t32[tid * 2]     = scnt0;
        t32[tid * 2 + 1] = scnt1;
        __syncthreads();
        int vv  = tid;
        int tb  = (vv >> 2) & 127;
        int slt = (vv & 3) >> 1;
        int hi  = vv & 1;
        unsigned tot = 0;
#pragma unroll
        for (int q = 0; q < 4; ++q)
            tot += (t32[(q * 128 + tb) * 2 + slt] >> (16 * hi)) & 0xFFFFu;
        atomicAdd(&dg[b0 + vv], tot);
    }
}

// ---------------- finalize: scale by 1/deg, ReLU ----------------
__global__ __launch_bounds__(256) void finalize_k(
    float* __restrict__ outp, const unsigned int* __restrict__ deg_u,
    const unsigned int* __restrict__ deg_v)
{
    int idx = blockIdx.x * blockDim.x + threadIdx.x;
    const int total = 2 * NN * DIM;
    for (; idx < total; idx += gridDim.x * blockDim.x) {
        int row = idx >> 6;
        unsigned d = (row < NN) ? deg_u[row] : deg_v[row - NN];
        float s = d ? (1.f / (float)d) : 0.f;
        float v = outp[idx] * s;
        outp[idx] = v > 0.f ? v : 0.f;
    }
}

extern "C" void kernel_launch(void* const* d_in, const int* in_sizes, int n_in,
                              void* d_out, int out_size, void* d_ws, size_t ws_size,
                              hipStream_t stream)
{
    const int*   adj = (const int*)d_in[0];
    const float* uf  = (const float*)d_in[1];
    const float* vf  = (const float*)d_in[2];
    const float* wu  = (const float*)d_in[3];
    const float* wv  = (const float*)d_in[4];
    float* outp = (float*)d_out;

    unsigned char* ws = (unsigned char*)d_ws;
    const size_t P_BYTES = (size_t)NR * (NN / 32) * 4 * 64 * 8 * 2;  // 5,242,880
    unsigned short* p_u = (unsigned short*)ws;
    unsigned short* p_v = (unsigned short*)(ws + P_BYTES);
    unsigned int*   deg = (unsigned int*)(ws + 2 * P_BYTES);   // deg_u | deg_v

    zero_k<<<1024, 256, 0, stream>>>(outp, deg);
    precompute_P<<<640, 256, 0, stream>>>(uf, vf, wu, wv, p_u, p_v);

    dim3 grid(NN / BM, NN / BK, 2);
    gemm_both<<<grid, 512, 0, stream>>>(adj, p_u, p_v, outp, deg);

    finalize_k<<<2048, 256, 0, stream>>>(outp, deg, deg + NN);
}

// Round 9
// 320.795 us; speedup vs baseline: 1.2147x; 1.2147x over previous
//
#include <hip/hip_runtime.h>

#define NN 8192
#define DIM 64
#define NR 5
#define BM 256      // output rows per block
#define BK 256      // K window per block = 8 ktiles of 32
#define NSTEP 8

typedef __attribute__((ext_vector_type(8))) short short8;
typedef __attribute__((ext_vector_type(4))) float f32x4;

__device__ inline unsigned short f2bf(float x) {
    unsigned u = __float_as_uint(x);
    return (unsigned short)((u + 0x7FFFu + ((u >> 16) & 1u)) >> 16);
}

__device__ __forceinline__ void gload_lds16(const void* g, void* l) {
    __builtin_amdgcn_global_load_lds(
        (const __attribute__((address_space(1))) void*)g,
        (__attribute__((address_space(3))) void*)l, 16, 0, 0);
}

// P fragment linear index (shorts) for (r, k, o).
// Bijection within a ktile: g=(k>>3)&3, j=k&7. The A-mask build uses the same
// (g,j)->k map, so the permutation cancels inside the MFMA.
__device__ inline size_t pfrag_idx(int r, int k, int o) {
    int ktile = k >> 5;
    int g     = (k >> 3) & 3;
    int j     = k & 7;
    int lane  = g * 16 + (o & 15);
    int n     = o >> 4;
    return ((((size_t)r * (NN / 32) + ktile) * 4 + n) * 64 + lane) * 8 + j;
}

// ---------------- zero-init ----------------
__global__ __launch_bounds__(256) void zero_k(float* __restrict__ outp,
                                              unsigned* __restrict__ deg)
{
    const int stride = gridDim.x * blockDim.x;
    int i = blockIdx.x * blockDim.x + threadIdx.x;
    int4 z = {0, 0, 0, 0};
    for (int idx = i; idx < 2 * NN * DIM / 4; idx += stride) ((int4*)outp)[idx] = z;
    for (int idx = i; idx < 2 * NN / 4; idx += stride) ((int4*)deg)[idx] = z;
}

// ---------------- P precompute: P[r][v][o] = sum_f feat[v][f] * W[r][f][o] ----
__global__ __launch_bounds__(256) void precompute_P(
    const float* __restrict__ u_feat, const float* __restrict__ v_feat,
    const float* __restrict__ w_u, const float* __restrict__ w_v,
    unsigned short* __restrict__ p_u, unsigned short* __restrict__ p_v)
{
    int wid  = (blockIdx.x * blockDim.x + threadIdx.x) >> 6;
    int lane = threadIdx.x & 63;
    const int tasks = 2 * NR * (NN / 32);
    if (wid >= tasks) return;
    int dir  = wid / (NR * (NN / 32));
    int rem  = wid % (NR * (NN / 32));
    int r    = rem / (NN / 32);
    int v0   = (rem % (NN / 32)) * 32;

    const float* feat = dir ? u_feat : v_feat;
    const float* w    = dir ? w_v : w_u;
    unsigned short* dst = dir ? p_v : p_u;

    float wreg[DIM];
#pragma unroll
    for (int f = 0; f < DIM; ++f) wreg[f] = w[(r * DIM + f) * DIM + lane];

    for (int v = v0; v < v0 + 32; ++v) {
        float x = feat[(size_t)v * DIM + lane];
        float acc = 0.f;
#pragma unroll
        for (int f = 0; f < DIM; ++f) acc += __shfl(x, f) * wreg[f];
        dst[pfrag_idx(r, v, lane)] = f2bf(acc);
    }
}

// ---------------- masked GEMM: R7 core + B staged through LDS ----------------
// TRANS=0: row=u, k=v. TRANS=1: row=v, k=u (4x4 transpose at staging).
// 512 thr = 8 waves; wave owns 32 rows (2 m-tiles) x all 4 n.
// Nibble tile [256][128B], XOR swizzle d^(row&31). B fragments: 20KB/step
// double-buffered in LDS via global_load_lds, issued one step ahead.
template <int TRANS>
__global__ __launch_bounds__(512, 4) void gemm_masked(
    const int* __restrict__ adj, const unsigned short* __restrict__ pfrag,
    float* __restrict__ outp, unsigned int* __restrict__ deg)
{
    __shared__ unsigned char  tile[BM][BK / 2];     // 32 KB nibbles
    __shared__ unsigned short bufB[2][NR * 4 * 512]; // 40 KB
    __shared__ unsigned int   cnt[BM];               // 1 KB

    const int tid  = threadIdx.x;
    const int lane = tid & 63;
    const int wv   = tid >> 6;
    const int b0   = blockIdx.x * BM;
    const int k0   = blockIdx.y * BK;
    const int kt0  = k0 >> 5;

    unsigned cpack = 0;

    // ---- B stage: 20 chunks of 1KB (r,n), wave-uniform dst, lane*16 src ----
    auto issueB = [&](int s) {
        const int p = s & 1;
        const int ktg = kt0 + s;
        for (int c = wv; c < 20; c += 8) {
            int r = c >> 2, n = c & 3;
            const unsigned short* src =
                pfrag + (((size_t)(r * (NN / 32) + ktg) * 4 + n) << 9) + lane * 8;
            gload_lds16(src, (void*)&bufB[p][c << 9]);
        }
    };

    issueB(0);   // overlaps with adj staging below

    // ================= adj staging =================
    if (TRANS == 0) {
        const int sub = tid & 15;            // 16 threads per row
        const int rq  = tid >> 4;            // 32 rows per round
        int4 pre[4], nxt[4];
        auto issue = [&](int rnd, int4* dst) {
            int row = rnd * 32 + rq;
            const int* base = adj + (size_t)(b0 + row) * NN + k0 + sub * 4;
#pragma unroll
            for (int it = 0; it < 4; ++it) dst[it] = *(const int4*)(base + it * 64);
        };
        issue(0, pre);
        for (int rnd = 0; rnd < 8; ++rnd) {
            if (rnd + 1 < 8) issue(rnd + 1, nxt);
            int row = rnd * 32 + rq;
            int c = 0;
#pragma unroll
            for (int it = 0; it < 4; ++it) {
                int4 a = pre[it];
                c += (a.x != 0) + (a.y != 0) + (a.z != 0) + (a.w != 0);
                unsigned pk = (unsigned)a.x | ((unsigned)a.y << 4) |
                              ((unsigned)a.z << 8) | ((unsigned)a.w << 12);
                int d  = it * 8 + (sub >> 1);
                int dp = d ^ (row & 31);
                *(unsigned short*)&tile[row][dp * 4 + (sub & 1) * 2] = (unsigned short)pk;
            }
            c += __shfl_xor(c, 1); c += __shfl_xor(c, 2);
            c += __shfl_xor(c, 4); c += __shfl_xor(c, 8);
            if (sub == 0) cnt[row] = (unsigned)c;
#pragma unroll
            for (int it = 0; it < 4; ++it) pre[it] = nxt[it];
        }
    } else {
        const int v4 = (tid & 63) * 4;
        int4 pre[4], nxt[4];
        auto issue = [&](int rnd, int4* dst) {
            int u0 = rnd * 32 + wv * 4;
#pragma unroll
            for (int c = 0; c < 4; ++c)
                dst[c] = *(const int4*)(adj + (size_t)(k0 + u0 + c) * NN + b0 + v4);
        };
        issue(0, pre);
        for (int rnd = 0; rnd < 8; ++rnd) {
            if (rnd + 1 < 8) issue(rnd + 1, nxt);
            const int* q0 = (const int*)&pre[0]; const int* q1 = (const int*)&pre[1];
            const int* q2 = (const int*)&pre[2]; const int* q3 = (const int*)&pre[3];
            int d = rnd * 4 + (wv >> 1);
#pragma unroll
            for (int cc = 0; cc < 4; ++cc) {
                int x0 = q0[cc], x1 = q1[cc], x2 = q2[cc], x3 = q3[cc];
                unsigned pk = (unsigned)x0 | ((unsigned)x1 << 4) |
                              ((unsigned)x2 << 8) | ((unsigned)x3 << 12);
                int row = v4 + cc;
                int dp  = d ^ (row & 31);
                *(unsigned short*)&tile[row][dp * 4 + (wv & 1) * 2] = (unsigned short)pk;
                cpack += (unsigned)((x0 != 0) + (x1 != 0) + (x2 != 0) + (x3 != 0)) << (8 * cc);
            }
#pragma unroll
            for (int c = 0; c < 4; ++c) pre[c] = nxt[c];
        }
    }
    __syncthreads();   // tile + bufB[0] ready (drains vmcnt & lgkm)

    // ================= main loop =================
    f32x4 acc[2][4];
#pragma unroll
    for (int m = 0; m < 2; ++m)
#pragma unroll
        for (int n = 0; n < 4; ++n) acc[m][n] = (f32x4){0.f, 0.f, 0.f, 0.f};

    const unsigned* t32 = (const unsigned*)&tile[0][0];
    const int mrow = wv * 32;

    for (int s = 0; s < NSTEP; ++s) {
        if (s + 1 < NSTEP) issueB(s + 1);
        const int p = s & 1;
        unsigned nib[2];
#pragma unroll
        for (int m = 0; m < 2; ++m) {
            int row = mrow + m * 16 + (lane & 15);
            int d   = s * 4 + (lane >> 4);
            nib[m] = t32[row * 32 + (d ^ (row & 31))];
        }
#pragma unroll
        for (int r = 0; r < NR; ++r) {
            short8 am[2];
#pragma unroll
            for (int m = 0; m < 2; ++m)
#pragma unroll
                for (int j = 0; j < 8; ++j)
                    am[m][j] = (short)((((nib[m] >> (4 * j)) & 0xFu) == (unsigned)(r + 1)) ? 0x3F80 : 0);
#pragma unroll
            for (int n = 0; n < 4; ++n) {
                short8 bf = *(const short8*)&bufB[p][((r * 4 + n) << 9) + lane * 8];
                acc[0][n] = __builtin_amdgcn_mfma_f32_16x16x32_bf16(am[0], bf, acc[0][n], 0, 0, 0);
                acc[1][n] = __builtin_amdgcn_mfma_f32_16x16x32_bf16(am[1], bf, acc[1][n], 0, 0, 0);
            }
        }
        __syncthreads();   // buf[s+1] landed; all waves done with buf[s]
    }

    // ================= epilogue: C atomics (col=lane&15, row=(lane>>4)*4+q) ====
#pragma unroll
    for (int m = 0; m < 2; ++m) {
        int rbase = b0 + mrow + m * 16 + ((lane >> 4) << 2);
#pragma unroll
        for (int n = 0; n < 4; ++n)
#pragma unroll
            for (int q = 0; q < 4; ++q)
                atomicAdd(&outp[(size_t)(rbase + q) * DIM + n * 16 + (lane & 15)], acc[m][n][q]);
    }

    // ================= degree reductions =================
    if (TRANS == 0) {
        if (tid < BM) atomicAdd(&deg[b0 + tid], cnt[tid]);
    } else {
        unsigned* sc = (unsigned*)&tile[0][0];
        sc[tid] = cpack;
        __syncthreads();
        if (tid < BM) {
            unsigned tot = 0;
            int base = tid >> 2, byte = tid & 3;
#pragma unroll
            for (int j = 0; j < 8; ++j) tot += (sc[j * 64 + base] >> (8 * byte)) & 0xFFu;
            atomicAdd(&deg[b0 + tid], tot);
        }
    }
}

// ---------------- finalize: scale by 1/deg, ReLU ----------------
__global__ __launch_bounds__(256) void finalize_k(
    float* __restrict__ outp, const unsigned int* __restrict__ deg_u,
    const unsigned int* __restrict__ deg_v)
{
    int idx = blockIdx.x * blockDim.x + threadIdx.x;
    const int total = 2 * NN * DIM;
    for (; idx < total; idx += gridDim.x * blockDim.x) {
        int row = idx >> 6;
        unsigned d = (row < NN) ? deg_u[row] : deg_v[row - NN];
        float s = d ? (1.f / (float)d) : 0.f;
        float v = outp[idx] * s;
        outp[idx] = v > 0.f ? v : 0.f;
    }
}

extern "C" void kernel_launch(void* const* d_in, const int* in_sizes, int n_in,
                              void* d_out, int out_size, void* d_ws, size_t ws_size,
                              hipStream_t stream)
{
    const int*   adj = (const int*)d_in[0];
    const float* uf  = (const float*)d_in[1];
    const float* vf  = (const float*)d_in[2];
    const float* wu  = (const float*)d_in[3];
    const float* wv  = (const float*)d_in[4];
    float* outp = (float*)d_out;

    unsigned char* ws = (unsigned char*)d_ws;
    const size_t P_BYTES = (size_t)NR * (NN / 32) * 4 * 64 * 8 * 2;  // 5,242,880
    unsigned short* p_u = (unsigned short*)ws;
    unsigned short* p_v = (unsigned short*)(ws + P_BYTES);
    unsigned int*   deg = (unsigned int*)(ws + 2 * P_BYTES);   // deg_u | deg_v

    zero_k<<<1024, 256, 0, stream>>>(outp, deg);
    precompute_P<<<640, 256, 0, stream>>>(uf, vf, wu, wv, p_u, p_v);

    dim3 grid(NN / BM, NN / BK);
    gemm_masked<0><<<grid, 512, 0, stream>>>(adj, p_u, outp, deg);
    gemm_masked<1><<<grid, 512, 0, stream>>>(adj, p_v, outp + (size_t)NN * DIM, deg + NN);

    finalize_k<<<2048, 256, 0, stream>>>(outp, deg, deg + NN);
}